// Round 5
// baseline (25.783 us; speedup 1.0000x reference)
//
#include <hip/hip_runtime.h>
#include <math.h>

#define SMALLF 1e-16f
#define EG 0.5772156649015329f

typedef float f32x4 __attribute__((ext_vector_type(4)));

__device__ __forceinline__ float rcpf(float x) { return __builtin_amdgcn_rcpf(x); }

// digamma for x > 0.3 via shift +4 then Stirling asymptotic.
// psi(x) = psi(x+4) - sum_{k=0..3} 1/(x+k)
// The 4-term reciprocal sum is collapsed to ONE reciprocal:
//   1/x + 1/(x+3) = (2x+3)/t,  1/(x+1) + 1/(x+2) = (2x+3)/(t+2),  t = x(x+3)
//   => s = (2x+3)*(2t+2) / (t*(t+2))
// psi(y) ~= ln(y) - 1/(2y) - 1/(12 y^2) + 1/(120 y^4) - 1/(252 y^6); y >= 4.3
// truncation < 1e-6, far inside the 2e-2 tolerance.
__device__ __forceinline__ float fast_digamma(float x) {
    float t  = x * (x + 3.0f);
    float s  = (2.0f * x + 3.0f) * (2.0f * t + 2.0f) * rcpf(t * (t + 2.0f));
    float y  = x + 4.0f;
    float w  = rcpf(y);
    float w2 = w * w;
    float poly = w2 * (8.3333333333e-2f - w2 * (8.3333333333e-3f - w2 * 3.9682539683e-3f));
    return __logf(y) - 0.5f * w - poly - s;
}

// Full 11-term Kumaraswamy series (reference semantics). Executed only when
// beta != 1 (never in the benchmark inputs) -- __noinline__ keeps its 22
// lgammaf calls from inflating hot-path VGPR use.
__device__ __noinline__ float kuma_series(float a, float b, float ab) {
    float ainv = 1.0f / (a + SMALLF);
    float lgb = lgammaf(b);
    float s = expf(lgammaf(ainv) + lgb - lgammaf(ainv + b)) / (1.0f + ab);
#pragma unroll 1
    for (int idx = 0; idx < 10; ++idx) {
        float m = (float)idx + 2.0f;
        float x = m * ainv;
        s += expf(lgammaf(x) + lgb - lgammaf(x + b)) / (m + ab);
    }
    return s;
}

// Cold path for the per-thread scalar constants (general alpha/beta).
__device__ __noinline__ float2 scalar_consts_cold(float al, float be) {
    float lb = lgammaf(al) + lgammaf(be) - lgammaf(al + be);
    float2 r;
    r.x = logf(expf(lb) + SMALLF);  // C = log(B(alpha,beta) + SMALL)
    r.y = be - 1.0f;                // beta - 1
    return r;
}

__device__ __forceinline__ float kl_elem(float a, float b, float alpha, float betam1, float C) {
    float ab   = fmaf(a, b, SMALLF);
    float arcp = rcpf(a + SMALLF);
    float binv = rcpf(b + SMALLF);
    float psi  = fast_digamma(b + SMALLF);

    float kl = (a - alpha) * arcp * (-EG - psi - binv)   // digamma cross-term
             + __logf(ab)                                // log(ab)
             + C                                         // hoisted scalar
             + (1.0f - b) * binv;                        // -(b-1)/(b+SMALL)

    if (__builtin_expect(betam1 != 0.0f, 0)) {
        kl += betam1 * b * kuma_series(a, b, ab);        // zero when beta == 1
    }
    return kl;
}

__device__ __forceinline__ f32x4 kl_vec4(f32x4 av, f32x4 bv,
                                         float al, float betam1, float C) {
    f32x4 o;
    o.x = kl_elem(av.x, bv.x, al, betam1, C);
    o.y = kl_elem(av.y, bv.y, al, betam1, C);
    o.z = kl_elem(av.z, bv.z, al, betam1, C);
    o.w = kl_elem(av.w, bv.w, al, betam1, C);
    return o;
}

#define KL_ITER 4

__global__ void __launch_bounds__(256)
kl_main(const float* __restrict__ A, const float* __restrict__ B,
        const float* __restrict__ alphaP, const float* __restrict__ betaP,
        float* __restrict__ out, int n) {
    // Per-thread uniform scalars; L2-broadcast loads, uniform branch.
    float al = alphaP[0], be = betaP[0];
    float C, betam1;
    if (al == 1.0f && be == 1.0f) {
        // lgamma(1)=lgamma(2)=0 -> B(1,1)=1 -> C=log(1f)=0 exactly
        C = 0.0f;
        betam1 = 0.0f;
    } else {
        float2 r = scalar_consts_cold(al, be);
        C = r.x;
        betam1 = r.y;
    }

    int n4 = n >> 2;
    const f32x4* A4 = (const f32x4*)A;
    const f32x4* B4 = (const f32x4*)B;
    f32x4*       O4 = (f32x4*)out;

    int tid    = blockIdx.x * blockDim.x + threadIdx.x;
    int stride = gridDim.x * blockDim.x;

    if (n4 == stride * KL_ITER) {
        // Exact-fit fast path (the benchmark shape): issue ALL loads up front
        // -> 8 outstanding 16B vector loads per thread, then compute + store.
        // Plain cached stores: nt-stores regressed (24.6 vs 22.3 us) -- they
        // force synchronous HBM retirement inside the kernel's lifetime.
        f32x4 av[KL_ITER], bv[KL_ITER];
#pragma unroll
        for (int k = 0; k < KL_ITER; ++k) {
            av[k] = A4[tid + k * stride];
            bv[k] = B4[tid + k * stride];
        }
#pragma unroll
        for (int k = 0; k < KL_ITER; ++k) {
            O4[tid + k * stride] = kl_vec4(av[k], bv[k], al, betam1, C);
        }
    } else {
        for (int i = tid; i < n4; i += stride) {
            O4[i] = kl_vec4(A4[i], B4[i], al, betam1, C);
        }
        // tail (n % 4 != 0) -- not hit for 4096*2048 but kept for correctness
        if (blockIdx.x == 0 && threadIdx.x == 0) {
            for (int k = n4 << 2; k < n; ++k)
                out[k] = kl_elem(A[k], B[k], al, betam1, C);
        }
    }
}

extern "C" void kernel_launch(void* const* d_in, const int* in_sizes, int n_in,
                              void* d_out, int out_size, void* d_ws, size_t ws_size,
                              hipStream_t stream) {
    const float* a     = (const float*)d_in[0];
    const float* b     = (const float*)d_in[1];
    const float* alpha = (const float*)d_in[2];
    const float* beta  = (const float*)d_in[3];
    float* out = (float*)d_out;
    int n = in_sizes[0];

    int n4 = n >> 2;
    int blocks = (n4 + 255) / 256;
    if (blocks > 2048) blocks = 2048;
    if (blocks < 1) blocks = 1;
    hipLaunchKernelGGL(kl_main, dim3(blocks), dim3(256), 0, stream,
                       a, b, alpha, beta, out, n);
}

// Round 6
// 23.286 us; speedup vs baseline: 1.1072x; 1.1072x over previous
//
#include <hip/hip_runtime.h>
#include <math.h>

#define SMALLF 1e-16f
#define EG 0.5772156649015329f

typedef float f32x4 __attribute__((ext_vector_type(4)));

__device__ __forceinline__ float rcpf(float x) { return __builtin_amdgcn_rcpf(x); }

// digamma for x > 0.3 via shift +4 then Stirling asymptotic.
// psi(x) = psi(x+4) - sum_{k=0..3} 1/(x+k)
// The 4-term reciprocal sum is collapsed to ONE reciprocal:
//   1/x + 1/(x+3) = (2x+3)/t,  1/(x+1) + 1/(x+2) = (2x+3)/(t+2),  t = x(x+3)
//   => s = (2x+3)*(2t+2) / (t*(t+2))
// psi(y) ~= ln(y) - 1/(2y) - 1/(12 y^2) + 1/(120 y^4) - 1/(252 y^6); y >= 4.3
// truncation < 1e-6, far inside the 2e-2 tolerance.
__device__ __forceinline__ float fast_digamma(float x) {
    float t  = x * (x + 3.0f);
    float s  = (2.0f * x + 3.0f) * (2.0f * t + 2.0f) * rcpf(t * (t + 2.0f));
    float y  = x + 4.0f;
    float w  = rcpf(y);
    float w2 = w * w;
    float poly = w2 * (8.3333333333e-2f - w2 * (8.3333333333e-3f - w2 * 3.9682539683e-3f));
    return __logf(y) - 0.5f * w - poly - s;
}

// Full 11-term Kumaraswamy series (reference semantics). Executed only when
// beta != 1 (never in the benchmark inputs) -- __noinline__ keeps its 22
// lgammaf calls from inflating hot-path VGPR use.
__device__ __noinline__ float kuma_series(float a, float b, float ab) {
    float ainv = 1.0f / (a + SMALLF);
    float lgb = lgammaf(b);
    float s = expf(lgammaf(ainv) + lgb - lgammaf(ainv + b)) / (1.0f + ab);
#pragma unroll 1
    for (int idx = 0; idx < 10; ++idx) {
        float m = (float)idx + 2.0f;
        float x = m * ainv;
        s += expf(lgammaf(x) + lgb - lgammaf(x + b)) / (m + ab);
    }
    return s;
}

// Cold path for the per-thread scalar constants (general alpha/beta).
__device__ __noinline__ float2 scalar_consts_cold(float al, float be) {
    float lb = lgammaf(al) + lgammaf(be) - lgammaf(al + be);
    float2 r;
    r.x = logf(expf(lb) + SMALLF);  // C = log(B(alpha,beta) + SMALL)
    r.y = be - 1.0f;                // beta - 1
    return r;
}

__device__ __forceinline__ float kl_elem(float a, float b, float alpha, float betam1, float C) {
    float ab   = fmaf(a, b, SMALLF);
    float arcp = rcpf(a + SMALLF);
    float binv = rcpf(b + SMALLF);
    float psi  = fast_digamma(b + SMALLF);

    float kl = (a - alpha) * arcp * (-EG - psi - binv)   // digamma cross-term
             + __logf(ab)                                // log(ab)
             + C                                         // hoisted scalar
             + (1.0f - b) * binv;                        // -(b-1)/(b+SMALL)

    if (__builtin_expect(betam1 != 0.0f, 0)) {
        kl += betam1 * b * kuma_series(a, b, ab);        // zero when beta == 1
    }
    return kl;
}

__device__ __forceinline__ f32x4 kl_vec4(f32x4 av, f32x4 bv,
                                         float al, float betam1, float C) {
    f32x4 o;
    o.x = kl_elem(av.x, bv.x, al, betam1, C);
    o.y = kl_elem(av.y, bv.y, al, betam1, C);
    o.z = kl_elem(av.z, bv.z, al, betam1, C);
    o.w = kl_elem(av.w, bv.w, al, betam1, C);
    return o;
}

__global__ void __launch_bounds__(256)
kl_main(const float* __restrict__ A, const float* __restrict__ B,
        const float* __restrict__ alphaP, const float* __restrict__ betaP,
        float* __restrict__ out, int n) {
    // Per-thread uniform scalars; L2-broadcast loads, uniform branch.
    float al = alphaP[0], be = betaP[0];
    float C, betam1;
    if (al == 1.0f && be == 1.0f) {
        // lgamma(1)=lgamma(2)=0 -> B(1,1)=1 -> C=log(1f)=0 exactly
        C = 0.0f;
        betam1 = 0.0f;
    } else {
        float2 r = scalar_consts_cold(al, be);
        C = r.x;
        betam1 = r.y;
    }

    int n4 = n >> 2;
    const f32x4* A4 = (const f32x4*)A;
    const f32x4* B4 = (const f32x4*)B;
    f32x4*       O4 = (f32x4*)out;

    // Simple grid-stride loop. Measured best (22.3 us): per-thread load
    // batching (round 4: 25.8) and nt-stores (round 3: 24.6) both regress --
    // TLP at ~32 waves/CU already saturates the memory system; extra
    // in-flight state per thread only costs VGPRs and issue clustering.
    int stride = gridDim.x * blockDim.x;
    for (int i = blockIdx.x * blockDim.x + threadIdx.x; i < n4; i += stride) {
        f32x4 av = A4[i];
        f32x4 bv = B4[i];
        O4[i] = kl_vec4(av, bv, al, betam1, C);
    }

    // tail (n % 4 != 0) -- not hit for 4096*2048 but kept for correctness
    if (blockIdx.x == 0 && threadIdx.x == 0) {
        for (int k = n4 << 2; k < n; ++k)
            out[k] = kl_elem(A[k], B[k], al, betam1, C);
    }
}

extern "C" void kernel_launch(void* const* d_in, const int* in_sizes, int n_in,
                              void* d_out, int out_size, void* d_ws, size_t ws_size,
                              hipStream_t stream) {
    const float* a     = (const float*)d_in[0];
    const float* b     = (const float*)d_in[1];
    const float* alpha = (const float*)d_in[2];
    const float* beta  = (const float*)d_in[3];
    float* out = (float*)d_out;
    int n = in_sizes[0];

    int n4 = n >> 2;
    int blocks = (n4 + 255) / 256;
    if (blocks > 2048) blocks = 2048;
    if (blocks < 1) blocks = 1;
    hipLaunchKernelGGL(kl_main, dim3(blocks), dim3(256), 0, stream,
                       a, b, alpha, beta, out, n);
}